// Round 6
// baseline (281.449 us; speedup 1.0000x reference)
//
#include <hip/hip_runtime.h>
#include <math.h>

#define Hn 6
#define Bn 512
#define Dn 2048
#define Cn 1000
#define Cpad 1024
#define TAUv 0.5f
#define KSPLIT 4
#define KPER (Dn / KSPLIT)   // 512 per k-split block
#define KT 32
#define NIT (KPER / KT)      // 16 K-iters per block

typedef unsigned int u32;
typedef unsigned short u16;
typedef __attribute__((ext_vector_type(8))) short short8;
typedef __attribute__((ext_vector_type(4))) float f32x4;

union FragU { u32 d[4]; short8 s; };

__device__ __forceinline__ u32 bf16_rne(float f) {
  const u32 u = __float_as_uint(f);
  return (u + 0x7FFFu + ((u >> 16) & 1u)) >> 16;
}
// pack two floats to bf16 pair (RNE), return residuals
__device__ __forceinline__ u32 pack_rne2(float f0, float f1, float& r0, float& r1) {
  const u32 b0 = bf16_rne(f0), b1 = bf16_rne(f1);
  r0 = f0 - __uint_as_float(b0 << 16);
  r1 = f1 - __uint_as_float(b1 << 16);
  return b0 | (b1 << 16);
}

// async global->LDS DMA, 16 B per lane; LDS dest = uniform base + lane*16
__device__ __forceinline__ void dma16(const void* g, void* l) {
  __builtin_amdgcn_global_load_lds(
      (const __attribute__((address_space(1))) u32*)g,
      (__attribute__((address_space(3))) u32*)l, 16, 0, 0);
}

// ============ feats fp32 -> Ah/Al bf16 (hi + residual, RNE) ============
__global__ __launch_bounds__(256) void aconv_k(const float* __restrict__ feats,
                                               u16* __restrict__ Ah, u16* __restrict__ Al)
{
  const size_t i4 = (size_t)blockIdx.x * 256 + threadIdx.x;  // float4 index, H*B*D/4 total
  const float4 v = ((const float4*)feats)[i4];
  float r0, r1, r2, r3, d0, d1, d2, d3;
  const u32 h0 = pack_rne2(v.x, v.y, r0, r1);
  const u32 h1 = pack_rne2(v.z, v.w, r2, r3);
  const u32 l0 = pack_rne2(r0, r1, d0, d1);
  const u32 l1 = pack_rne2(r2, r3, d2, d3);
  ((uint2*)Ah)[i4] = make_uint2(h0, h1);
  ((uint2*)Al)[i4] = make_uint2(l0, l1);
}

// ============ W fp32 [D][C] -> Bh/Bl bf16 transposed [Cpad][D] ============
__global__ __launch_bounds__(256) void bconv_k(const float* __restrict__ W,
                                               u16* __restrict__ Bh, u16* __restrict__ Bl)
{
  const int h  = blockIdx.z;
  const int d0 = blockIdx.x * 64;
  const int n0 = blockIdx.y * 64;
  __shared__ float tile[64][65];   // pad 65 -> conflict-light transposed reads
  const int t = threadIdx.x;

  // read phase: coalesced float4 rows of W
#pragma unroll
  for (int rr = 0; rr < 4; ++rr) {
    const int d  = rr * 16 + (t >> 4);
    const int n4 = (t & 15) * 4;
    const float* src = W + ((size_t)h * Dn + d0 + d) * Cn;
    float4 v = make_float4(0.f, 0.f, 0.f, 0.f);
    const int ng = n0 + n4;
    if (ng + 3 < Cn) {
      v = *(const float4*)(src + ng);
    } else {
      if (ng + 0 < Cn) v.x = src[ng + 0];
      if (ng + 1 < Cn) v.y = src[ng + 1];
      if (ng + 2 < Cn) v.z = src[ng + 2];
      if (ng + 3 < Cn) v.w = src[ng + 3];
    }
    tile[d][n4 + 0] = v.x; tile[d][n4 + 1] = v.y;
    tile[d][n4 + 2] = v.z; tile[d][n4 + 3] = v.w;
  }
  __syncthreads();

  // write phase: transposed, coalesced along d, hi+lo bf16
#pragma unroll
  for (int rr = 0; rr < 4; ++rr) {
    const int nl = rr * 16 + (t >> 4);
    const int d4 = (t & 15) * 4;
    const float f0 = tile[d4 + 0][nl], f1 = tile[d4 + 1][nl];
    const float f2 = tile[d4 + 2][nl], f3 = tile[d4 + 3][nl];
    float r0, r1, r2, r3, q0, q1, q2, q3;
    const u32 h0 = pack_rne2(f0, f1, r0, r1);
    const u32 h1 = pack_rne2(f2, f3, r2, r3);
    const u32 l0 = pack_rne2(r0, r1, q0, q1);
    const u32 l1 = pack_rne2(r2, r3, q2, q3);
    const size_t idx = ((size_t)h * Cpad + n0 + nl) * Dn + d0 + d4;
    *(uint2*)(Bh + idx) = make_uint2(h0, h1);
    *(uint2*)(Bl + idx) = make_uint2(l0, l1);
  }
}

// ============ bf16 MFMA GEMM, m97-style DMA staging, K-split x4, atomic-acc ============
// 128x128 block, 256 thr = 4 waves (2x2), wave-tile 64x64, 3-term split-bf16.
__global__ __launch_bounds__(256, 3) void gemm_k(
    const u16* __restrict__ AhG, const u16* __restrict__ AlG,
    const u16* __restrict__ BhG, const u16* __restrict__ BlG,
    const float* __restrict__ bias, float* __restrict__ logits)
{
  const int h  = blockIdx.z / KSPLIT;
  const int kz = blockIdx.z % KSPLIT;
  const int m0 = blockIdx.y * 128;
  const int n0 = blockIdx.x * 128;
  const int kbase = kz * KPER;

  __shared__ __align__(16) short Ah[4][128][8];   // [k-chunk][m][8 bf16] 8 KB
  __shared__ __align__(16) short Al[4][128][8];
  __shared__ __align__(16) short Bh[4][128][8];   // [k-chunk][n][8 bf16]
  __shared__ __align__(16) short Bl[4][128][8];

  const int t = threadIdx.x;
  const int lane = t & 63;
  const int w    = t >> 6;
  const int wm   = (w & 1) * 64;
  const int wn   = (w >> 1) * 64;
  const int fl   = lane & 15;
  const int fq   = lane >> 4;

  // this wave's DMA source: wave 0->Ah, 1->Al, 2->Bh, 3->Bl
  const u16* gmat = (w == 0) ? AhG : (w == 1) ? AlG : (w == 2) ? BhG : BlG;
  const size_t rowbase = (w < 2) ? ((size_t)h * Bn + m0) : ((size_t)h * Cpad + n0);
  short* lbase = (w == 0) ? &Ah[0][0][0] : (w == 1) ? &Al[0][0][0]
               : (w == 2) ? &Bh[0][0][0] : &Bl[0][0][0];
  const u16* grow = gmat + (rowbase + lane) * (size_t)Dn + kbase;   // + lane row
  const u16* grow64 = grow + (size_t)64 * Dn;

  f32x4 acc[4][4];
#pragma unroll
  for (int i = 0; i < 4; ++i)
#pragma unroll
    for (int j = 0; j < 4; ++j) acc[i][j] = (f32x4){0.f, 0.f, 0.f, 0.f};

  for (int it = 0; it < NIT; ++it) {
    const int kk = it * KT;
    // 8 DMA loads per wave: [chunk c][half hf] -> 64 rows x 16 B each
#pragma unroll
    for (int c = 0; c < 4; ++c) {
      dma16(grow   + kk + c * 8, lbase + c * 1024);         // rows 0..63
      dma16(grow64 + kk + c * 8, lbase + c * 1024 + 512);   // rows 64..127
    }
    __syncthreads();   // drains vmcnt -> DMA landed, prev reads done

    FragU ah[4], al[4];
#pragma unroll
    for (int mt = 0; mt < 4; ++mt) {
      const int m = wm + mt * 16 + fl;
      ah[mt].s = *(const short8*)(&Ah[fq][m][0]);
      al[mt].s = *(const short8*)(&Al[fq][m][0]);
    }
#pragma unroll
    for (int nt = 0; nt < 4; ++nt) {
      const int n = wn + nt * 16 + fl;
      FragU bh, bl;
      bh.s = *(const short8*)(&Bh[fq][n][0]);
      bl.s = *(const short8*)(&Bl[fq][n][0]);
#pragma unroll
      for (int mt = 0; mt < 4; ++mt) {
        acc[mt][nt] = __builtin_amdgcn_mfma_f32_16x16x32_bf16(ah[mt].s, bh.s, acc[mt][nt], 0, 0, 0);
        acc[mt][nt] = __builtin_amdgcn_mfma_f32_16x16x32_bf16(ah[mt].s, bl.s, acc[mt][nt], 0, 0, 0);
        acc[mt][nt] = __builtin_amdgcn_mfma_f32_16x16x32_bf16(al[mt].s, bh.s, acc[mt][nt], 0, 0, 0);
      }
    }
    __syncthreads();   // all waves done reading before next iter's DMA overwrite
  }

  // epilogue: atomic accumulate (+bias once, from the kz==0 block)
#pragma unroll
  for (int nt = 0; nt < 4; ++nt) {
    const int col = n0 + wn + nt * 16 + fl;
    if (col >= Cn) continue;
    const float bv = (kz == 0) ? bias[(size_t)h * Cn + col] : 0.f;
#pragma unroll
    for (int mt = 0; mt < 4; ++mt) {
      const int rbase = m0 + wm + mt * 16 + fq * 4;
#pragma unroll
      for (int r = 0; r < 4; ++r)
        atomicAdd(&logits[((size_t)h * Bn + rbase + r) * Cn + col], acc[mt][nt][r] + bv);
    }
  }
}

// ============ per-row softmax stats: one wave per (h,b) row ============
__global__ __launch_bounds__(256) void conf_k(const float* __restrict__ logits,
                                              float* __restrict__ ms,
                                              float* __restrict__ ss,
                                              float* __restrict__ scalars)
{
  if (blockIdx.x == 0 && threadIdx.x == 0) { scalars[0] = 0.f; scalars[1] = 0.f; }
  const int w = threadIdx.x >> 6, lane = threadIdx.x & 63;
  const int r = blockIdx.x * 4 + w;                 // row = h*Bn + b
  const float* row = logits + (size_t)r * Cn;

  float vv[16];
#pragma unroll
  for (int i = 0; i < 4; ++i) {
    const int c4 = i * 256 + lane * 4;
    if (c4 + 3 < Cn) {
      const float4 v = *(const float4*)(row + c4);
      vv[4 * i] = v.x; vv[4 * i + 1] = v.y; vv[4 * i + 2] = v.z; vv[4 * i + 3] = v.w;
    } else {
#pragma unroll
      for (int j = 0; j < 4; ++j)
        vv[4 * i + j] = (c4 + j < Cn) ? row[c4 + j] : -3.4e38f;
    }
  }
  float m = -3.4e38f;
#pragma unroll
  for (int i = 0; i < 16; ++i) m = fmaxf(m, vv[i]);
#pragma unroll
  for (int off = 32; off >= 1; off >>= 1) m = fmaxf(m, __shfl_xor(m, off));
  float s = 0.f;
#pragma unroll
  for (int i = 0; i < 16; ++i) s += (vv[i] > -3.0e38f) ? expf(vv[i] - m) : 0.f;
#pragma unroll
  for (int off = 32; off >= 1; off >>= 1) s += __shfl_xor(s, off);
  if (lane == 0) { ms[r] = m; ss[r] = s; }
}

// ============ route + gather + argmax + CE (one block per sample) ============
__global__ __launch_bounds__(256) void pick_k(
    const float* __restrict__ logits, const float* __restrict__ ms,
    const float* __restrict__ ss, const int* __restrict__ y,
    float* __restrict__ out, float* __restrict__ out_exit,
    float* __restrict__ scalars)
{
  const int b = blockIdx.x, t = threadIdx.x;

  int first = -1, best = 0;
  float bestc = -3.4e38f;
#pragma unroll
  for (int h = 0; h < Hn; ++h) {
    const float c = 1.0f / ss[h * Bn + b];          // max softmax prob
    if (first < 0 && c >= TAUv) first = h;
    if (c > bestc) { bestc = c; best = h; }         // strict > keeps first occurrence
  }
  const int ex = (first >= 0) ? first : best;
  const float* row = logits + ((size_t)ex * Bn + b) * Cn;

  const int c4 = t * 4;
  float vv[4] = {-3.4e38f, -3.4e38f, -3.4e38f, -3.4e38f};
  if (c4 + 3 < Cn) {
    const float4 v = *(const float4*)(row + c4);
    vv[0] = v.x; vv[1] = v.y; vv[2] = v.z; vv[3] = v.w;
  } else {
#pragma unroll
    for (int j = 0; j < 4; ++j) if (c4 + j < Cn) vv[j] = row[c4 + j];
  }
  float vm = -3.4e38f; int im = 1 << 30;
#pragma unroll
  for (int j = 0; j < 4; ++j) {
    const int c = c4 + j;
    if (c < Cn) {
      out[(size_t)b * Cn + c] = vv[j];
      if (vv[j] > vm) { vm = vv[j]; im = c; }       // ascending c keeps first max
    }
  }
  const int lane = t & 63, w = t >> 6;
#pragma unroll
  for (int off = 32; off >= 1; off >>= 1) {
    const float ov = __shfl_xor(vm, off);
    const int   oi = __shfl_xor(im, off);
    if (ov > vm || (ov == vm && oi < im)) { vm = ov; im = oi; }
  }
  __shared__ float rm[4]; __shared__ int ri[4];
  if (lane == 0) { rm[w] = vm; ri[w] = im; }
  __syncthreads();
  if (t == 0) {
    float bm = rm[0]; int bi = ri[0];
    for (int q = 1; q < 4; ++q)
      if (rm[q] > bm || (rm[q] == bm && ri[q] < bi)) { bm = rm[q]; bi = ri[q]; }
    const int yt = y[b];
    const float lp = row[yt] - ms[ex * Bn + b] - logf(ss[ex * Bn + b]);
    out_exit[b] = (float)ex;
    atomicAdd(&scalars[0], -lp * (1.0f / (float)Bn));
    atomicAdd(&scalars[1], ((bi == yt) ? 1.f : 0.f) * (1.0f / (float)Bn));
  }
}

extern "C" void kernel_launch(void* const* d_in, const int* in_sizes, int n_in,
                              void* d_out, int out_size, void* d_ws, size_t ws_size,
                              hipStream_t stream) {
  const float* feats = (const float*)d_in[0];   // [H,B,D]
  const float* W     = (const float*)d_in[1];   // [H,D,C]
  const float* bias  = (const float*)d_in[2];   // [H,C]
  const int*   y     = (const int*)d_in[3];     // [B]
  float* out = (float*)d_out;                   // [B*C | B | 1 | 1]

  // ws layout (bytes):
  //   logits  H*B*C f32          = 12,288,000
  //   ms, ss  H*B f32 each       =     24,576
  //   Ah, Al  H*B*D bf16 each    = 12,582,912 x2
  //   Bh, Bl  H*Cpad*D bf16 each = 25,165,824 x2
  float* logits = (float*)d_ws;
  float* ms     = logits + (size_t)Hn * Bn * Cn;
  float* ss     = ms + Hn * Bn;
  u16*   AhG    = (u16*)(ss + Hn * Bn);
  u16*   AlG    = AhG + (size_t)Hn * Bn * Dn;
  u16*   BhG    = AlG + (size_t)Hn * Bn * Dn;
  u16*   BlG    = BhG + (size_t)Hn * Cpad * Dn;

  float* out_exit    = out + (size_t)Bn * Cn;
  float* out_scalars = out + (size_t)Bn * Cn + Bn;

  hipMemsetAsync(logits, 0, (size_t)Hn * Bn * Cn * sizeof(float), stream);
  aconv_k<<<(Hn * Bn * Dn / 4) / 256, 256, 0, stream>>>(feats, AhG, AlG);
  bconv_k<<<dim3(Dn / 64, Cpad / 64, Hn), 256, 0, stream>>>(W, BhG, BlG);
  gemm_k<<<dim3(Cpad / 128, Bn / 128, Hn * KSPLIT), 256, 0, stream>>>(
      AhG, AlG, BhG, BlG, bias, logits);
  conf_k<<<(Hn * Bn) / 4, 256, 0, stream>>>(logits, ms, ss, out_scalars);
  pick_k<<<Bn, 256, 0, stream>>>(logits, ms, ss, y, out, out_exit, out_scalars);
}

// Round 7
// 198.234 us; speedup vs baseline: 1.4198x; 1.4198x over previous
//
#include <hip/hip_runtime.h>
#include <math.h>

#define Hn 6
#define Bn 512
#define Dn 2048
#define Cn 1000
#define Cpad 1024
#define TAUv 0.5f
#define KSPLIT 4
#define KPER (Dn / KSPLIT)   // 512
#define KT 32
#define NIT (KPER / KT)      // 16
#define NKT (Dn / KT)        // 64 ktiles total

typedef unsigned int u32;
typedef unsigned short u16;
typedef __attribute__((ext_vector_type(8))) short short8;
typedef __attribute__((ext_vector_type(4))) float f32x4;

union FragU { u32 d[4]; short8 s; };

__device__ __forceinline__ u32 bf16_rne(float f) {
  const u32 u = __float_as_uint(f);
  return (u + 0x7FFFu + ((u >> 16) & 1u)) >> 16;
}
// pack two floats to one dword of bf16 (RNE; f0 -> low half), return residuals
__device__ __forceinline__ u32 pack_rne2(float f0, float f1, float& r0, float& r1) {
  const u32 b0 = bf16_rne(f0), b1 = bf16_rne(f1);
  r0 = f0 - __uint_as_float(b0 << 16);
  r1 = f1 - __uint_as_float(b1 << 16);
  return b0 | (b1 << 16);
}

// async global->LDS DMA, 16 B/lane; LDS dest = wave-uniform base + lane*16
__device__ __forceinline__ void dma16(const void* g, void* l) {
  __builtin_amdgcn_global_load_lds(
      (const __attribute__((address_space(1))) u32*)g,
      (__attribute__((address_space(3))) u32*)l, 16, 0, 0);
}

// convert 8 fp32 -> hi/lo bf16 16B chunks
__device__ __forceinline__ void pack8(const float* rr, uint4& hv, uint4& lv) {
  float x0, x1, x2, x3, y0, y1, y2, y3, d;
  hv.x = pack_rne2(rr[0], rr[1], x0, x1);
  hv.y = pack_rne2(rr[2], rr[3], x2, x3);
  hv.z = pack_rne2(rr[4], rr[5], y0, y1);
  hv.w = pack_rne2(rr[6], rr[7], y2, y3);
  lv.x = pack_rne2(x0, x1, d, d);
  lv.y = pack_rne2(x2, x3, d, d);
  lv.z = pack_rne2(y0, y1, d, d);
  lv.w = pack_rne2(y2, y3, d, d);
}

// ============ feats fp32 [H][B][D] -> k-tiled Ah/Al: [H][64][4][512][8] ============
__global__ __launch_bounds__(256) void aconv_k(const float* __restrict__ feats,
                                               u16* __restrict__ Ah, u16* __restrict__ Al)
{
  const int t  = blockIdx.x;    // ktile 0..63
  const int rg = blockIdx.y;    // row group 0..3
  const int h  = blockIdx.z;
  const int r0 = rg * 128;
  __shared__ float tile[128][33];
  const int tid = threadIdx.x;

#pragma unroll
  for (int i = 0; i < 4; ++i) {
    const int f = i * 256 + tid;     // 0..1023 float4 tasks
    const int r = f >> 3, q = f & 7;
    const float4 v = *(const float4*)(feats + ((size_t)(h * Bn + r0 + r) * Dn + t * 32 + q * 4));
    tile[r][q * 4 + 0] = v.x; tile[r][q * 4 + 1] = v.y;
    tile[r][q * 4 + 2] = v.z; tile[r][q * 4 + 3] = v.w;
  }
  __syncthreads();
#pragma unroll
  for (int i = 0; i < 2; ++i) {
    const int j = i * 256 + tid;     // 0..511 chunk tasks
    const int c = j >> 7, r = j & 127;
    float rr[8];
#pragma unroll
    for (int e = 0; e < 8; ++e) rr[e] = tile[r][c * 8 + e];
    uint4 hv, lv;
    pack8(rr, hv, lv);
    const size_t o = (((size_t)(h * 64 + t) * 4 + c) * 512 + r0 + r);
    ((uint4*)Ah)[o] = hv;
    ((uint4*)Al)[o] = lv;
  }
}

// ============ W fp32 [H][D][C] -> k-tiled transposed Bh/Bl: [H][64][4][1024][8] ============
__global__ __launch_bounds__(256) void bconv_k(const float* __restrict__ W,
                                               u16* __restrict__ Bh, u16* __restrict__ Bl)
{
  const int t  = blockIdx.x;    // ktile 0..63
  const int ng = blockIdx.y;    // n group 0..7
  const int h  = blockIdx.z;
  const int n0 = ng * 128;
  __shared__ float tile[32][129];
  const int tid = threadIdx.x;

#pragma unroll
  for (int i = 0; i < 4; ++i) {
    const int f = i * 256 + tid;     // 0..1023
    const int k = f >> 5, q = f & 31;
    const int n = n0 + q * 4;
    const float* src = W + ((size_t)h * Dn + t * 32 + k) * Cn;
    float4 v = make_float4(0.f, 0.f, 0.f, 0.f);
    if (n + 3 < Cn) {
      v = *(const float4*)(src + n);
    } else {
      if (n + 0 < Cn) v.x = src[n + 0];
      if (n + 1 < Cn) v.y = src[n + 1];
      if (n + 2 < Cn) v.z = src[n + 2];
      if (n + 3 < Cn) v.w = src[n + 3];
    }
    tile[k][q * 4 + 0] = v.x; tile[k][q * 4 + 1] = v.y;
    tile[k][q * 4 + 2] = v.z; tile[k][q * 4 + 3] = v.w;
  }
  __syncthreads();
#pragma unroll
  for (int i = 0; i < 2; ++i) {
    const int j = i * 256 + tid;     // 0..511
    const int c = j >> 7, n = j & 127;
    float rr[8];
#pragma unroll
    for (int e = 0; e < 8; ++e) rr[e] = tile[c * 8 + e][n];
    uint4 hv, lv;
    pack8(rr, hv, lv);
    const size_t o = (((size_t)(h * 64 + t) * 4 + c) * 1024 + n0 + n);
    ((uint4*)Bh)[o] = hv;
    ((uint4*)Bl)[o] = lv;
  }
}

// ============ split-bf16 MFMA GEMM, coalesced DMA staging, K-split partials ============
// 128x128 block, 256 thr = 4 waves (2x2), wave-tile 64x64, 3-term split-bf16.
__global__ __launch_bounds__(256, 3) void gemm_k(
    const u16* __restrict__ AhG, const u16* __restrict__ AlG,
    const u16* __restrict__ BhG, const u16* __restrict__ BlG,
    const float* __restrict__ bias, float* __restrict__ logits)
{
  const int h  = blockIdx.z >> 2;
  const int kz = blockIdx.z & 3;
  const int m0 = blockIdx.y * 128;
  const int n0 = blockIdx.x * 128;

  __shared__ __align__(16) short Ah[4][128][8];   // 8 KB each
  __shared__ __align__(16) short Al[4][128][8];
  __shared__ __align__(16) short Bh[4][128][8];
  __shared__ __align__(16) short Bl[4][128][8];

  const int t = threadIdx.x;
  const int lane = t & 63;
  const int w    = t >> 6;
  const int wm   = (w & 1) * 64;
  const int wn   = (w >> 1) * 64;
  const int fl   = lane & 15;
  const int fq   = lane >> 4;

  // wave w stages matrix w; k-tiled layout -> each dma16 is a 1KB coalesced burst
  const u16* gmat = (w == 0) ? AhG : (w == 1) ? AlG : (w == 2) ? BhG : BlG;
  const int  R    = (w < 2) ? 512 : 1024;
  const int  row0 = (w < 2) ? m0 : n0;
  short* lbase = (w == 0) ? &Ah[0][0][0] : (w == 1) ? &Al[0][0][0]
               : (w == 2) ? &Bh[0][0][0] : &Bl[0][0][0];
  const uint4* g0 = (const uint4*)gmat
                  + ((size_t)(h * 64 + kz * NIT) * 4) * R + row0 + lane;

  f32x4 acc[4][4];
#pragma unroll
  for (int i = 0; i < 4; ++i)
#pragma unroll
    for (int j = 0; j < 4; ++j) acc[i][j] = (f32x4){0.f, 0.f, 0.f, 0.f};

  for (int it = 0; it < NIT; ++it) {
    const size_t ito = (size_t)(it * 4) * R;
#pragma unroll
    for (int c = 0; c < 4; ++c) {
      dma16(g0 + ito + (size_t)c * R,      lbase + (c * 128) * 8);        // rows 0..63
      dma16(g0 + ito + (size_t)c * R + 64, lbase + (c * 128 + 64) * 8);   // rows 64..127
    }
    __syncthreads();   // vmcnt(0) drain: DMA landed

    FragU ah[4], al[4];
#pragma unroll
    for (int mt = 0; mt < 4; ++mt) {
      const int m = wm + mt * 16 + fl;
      ah[mt].s = *(const short8*)(&Ah[fq][m][0]);
      al[mt].s = *(const short8*)(&Al[fq][m][0]);
    }
#pragma unroll
    for (int nt = 0; nt < 4; ++nt) {
      const int n = wn + nt * 16 + fl;
      FragU bh, bl;
      bh.s = *(const short8*)(&Bh[fq][n][0]);
      bl.s = *(const short8*)(&Bl[fq][n][0]);
#pragma unroll
      for (int mt = 0; mt < 4; ++mt) {
        acc[mt][nt] = __builtin_amdgcn_mfma_f32_16x16x32_bf16(ah[mt].s, bh.s, acc[mt][nt], 0, 0, 0);
        acc[mt][nt] = __builtin_amdgcn_mfma_f32_16x16x32_bf16(ah[mt].s, bl.s, acc[mt][nt], 0, 0, 0);
        acc[mt][nt] = __builtin_amdgcn_mfma_f32_16x16x32_bf16(al[mt].s, bh.s, acc[mt][nt], 0, 0, 0);
      }
    }
    __syncthreads();   // all reads done before next iter's DMA overwrites
  }

  // epilogue: plain stores into this kz's partial buffer (+bias on kz 0)
  float* part = logits + (size_t)kz * ((size_t)Hn * Bn * Cn);
#pragma unroll
  for (int nt = 0; nt < 4; ++nt) {
    const int col = n0 + wn + nt * 16 + fl;
    if (col >= Cn) continue;
    const float bv = (kz == 0) ? bias[(size_t)h * Cn + col] : 0.f;
#pragma unroll
    for (int mt = 0; mt < 4; ++mt) {
      const int rbase = m0 + wm + mt * 16 + fq * 4;
#pragma unroll
      for (int r = 0; r < 4; ++r)
        part[((size_t)h * Bn + rbase + r) * Cn + col] = acc[mt][nt][r] + bv;
    }
  }
}

// ============ per-row softmax stats over summed partials: one wave per (h,b) ============
__global__ __launch_bounds__(256) void conf_k(const float* __restrict__ logits,
                                              float* __restrict__ ms,
                                              float* __restrict__ ss,
                                              float* __restrict__ scalars)
{
  if (blockIdx.x == 0 && threadIdx.x == 0) { scalars[0] = 0.f; scalars[1] = 0.f; }
  const int w = threadIdx.x >> 6, lane = threadIdx.x & 63;
  const int r = blockIdx.x * 4 + w;                 // row = h*Bn + b
  const float* p = logits + (size_t)r * Cn;
  const size_t S = (size_t)Hn * Bn * Cn;

  float vv[16];
#pragma unroll
  for (int i = 0; i < 4; ++i) {
    const int c4 = i * 256 + lane * 4;
    if (c4 + 3 < Cn) {
      const float4 v0 = *(const float4*)(p + c4);
      const float4 v1 = *(const float4*)(p + S + c4);
      const float4 v2 = *(const float4*)(p + 2 * S + c4);
      const float4 v3 = *(const float4*)(p + 3 * S + c4);
      vv[4 * i + 0] = v0.x + v1.x + v2.x + v3.x;
      vv[4 * i + 1] = v0.y + v1.y + v2.y + v3.y;
      vv[4 * i + 2] = v0.z + v1.z + v2.z + v3.z;
      vv[4 * i + 3] = v0.w + v1.w + v2.w + v3.w;
    } else {
#pragma unroll
      for (int j = 0; j < 4; ++j) {
        const int c = c4 + j;
        vv[4 * i + j] = (c < Cn) ? p[c] + p[S + c] + p[2 * S + c] + p[3 * S + c] : -3.4e38f;
      }
    }
  }
  float m = -3.4e38f;
#pragma unroll
  for (int i = 0; i < 16; ++i) m = fmaxf(m, vv[i]);
#pragma unroll
  for (int off = 32; off >= 1; off >>= 1) m = fmaxf(m, __shfl_xor(m, off));
  float s = 0.f;
#pragma unroll
  for (int i = 0; i < 16; ++i) s += (vv[i] > -3.0e38f) ? expf(vv[i] - m) : 0.f;
#pragma unroll
  for (int off = 32; off >= 1; off >>= 1) s += __shfl_xor(s, off);
  if (lane == 0) { ms[r] = m; ss[r] = s; }
}

// ============ route + gather (summed partials) + argmax + CE ============
__global__ __launch_bounds__(256) void pick_k(
    const float* __restrict__ logits, const float* __restrict__ ms,
    const float* __restrict__ ss, const int* __restrict__ y,
    float* __restrict__ out, float* __restrict__ out_exit,
    float* __restrict__ scalars)
{
  const int b = blockIdx.x, t = threadIdx.x;
  const size_t S = (size_t)Hn * Bn * Cn;

  int first = -1, best = 0;
  float bestc = -3.4e38f;
#pragma unroll
  for (int h = 0; h < Hn; ++h) {
    const float c = 1.0f / ss[h * Bn + b];          // max softmax prob
    if (first < 0 && c >= TAUv) first = h;
    if (c > bestc) { bestc = c; best = h; }         // strict > keeps first occurrence
  }
  const int ex = (first >= 0) ? first : best;
  const float* p = logits + ((size_t)ex * Bn + b) * Cn;

  const int c4 = t * 4;
  float vv[4] = {-3.4e38f, -3.4e38f, -3.4e38f, -3.4e38f};
  if (c4 + 3 < Cn) {
    const float4 v0 = *(const float4*)(p + c4);
    const float4 v1 = *(const float4*)(p + S + c4);
    const float4 v2 = *(const float4*)(p + 2 * S + c4);
    const float4 v3 = *(const float4*)(p + 3 * S + c4);
    vv[0] = v0.x + v1.x + v2.x + v3.x;
    vv[1] = v0.y + v1.y + v2.y + v3.y;
    vv[2] = v0.z + v1.z + v2.z + v3.z;
    vv[3] = v0.w + v1.w + v2.w + v3.w;
  }
  float vm = -3.4e38f; int im = 1 << 30;
#pragma unroll
  for (int j = 0; j < 4; ++j) {
    const int c = c4 + j;
    if (c < Cn) {
      out[(size_t)b * Cn + c] = vv[j];
      if (vv[j] > vm) { vm = vv[j]; im = c; }       // ascending c keeps first max
    }
  }
  const int lane = t & 63, w = t >> 6;
#pragma unroll
  for (int off = 32; off >= 1; off >>= 1) {
    const float ov = __shfl_xor(vm, off);
    const int   oi = __shfl_xor(im, off);
    if (ov > vm || (ov == vm && oi < im)) { vm = ov; im = oi; }
  }
  __shared__ float rm[4]; __shared__ int ri[4];
  if (lane == 0) { rm[w] = vm; ri[w] = im; }
  __syncthreads();
  if (t == 0) {
    float bm = rm[0]; int bi = ri[0];
    for (int q = 1; q < 4; ++q)
      if (rm[q] > bm || (rm[q] == bm && ri[q] < bi)) { bm = rm[q]; bi = ri[q]; }
    const int yt = y[b];
    const float ryt = p[yt] + p[S + yt] + p[2 * S + yt] + p[3 * S + yt];
    const float lp = ryt - ms[ex * Bn + b] - logf(ss[ex * Bn + b]);
    out_exit[b] = (float)ex;
    atomicAdd(&scalars[0], -lp * (1.0f / (float)Bn));
    atomicAdd(&scalars[1], ((bi == yt) ? 1.f : 0.f) * (1.0f / (float)Bn));
  }
}

extern "C" void kernel_launch(void* const* d_in, const int* in_sizes, int n_in,
                              void* d_out, int out_size, void* d_ws, size_t ws_size,
                              hipStream_t stream) {
  const float* feats = (const float*)d_in[0];   // [H,B,D]
  const float* W     = (const float*)d_in[1];   // [H,D,C]
  const float* bias  = (const float*)d_in[2];   // [H,C]
  const int*   y     = (const int*)d_in[3];     // [B]
  float* out = (float*)d_out;                   // [B*C | B | 1 | 1]

  // ws layout:
  //   logits partials  KSPLIT * H*B*C f32 = 49,152,000 B
  //   ms, ss           H*B f32 each
  //   AhG, AlG         [H][64][4][512][8]  bf16 = 12,582,912 B each
  //   BhG, BlG         [H][64][4][1024][8] bf16 = 25,165,824 B each
  //   total ~124.7 MB
  float* logits = (float*)d_ws;
  float* ms     = logits + (size_t)KSPLIT * Hn * Bn * Cn;
  float* ss     = ms + Hn * Bn;
  u16*   AhG    = (u16*)(ss + Hn * Bn);
  u16*   AlG    = AhG + (size_t)Hn * Bn * Dn;
  u16*   BhG    = AlG + (size_t)Hn * Bn * Dn;
  u16*   BlG    = BhG + (size_t)Hn * Cpad * Dn;

  float* out_exit    = out + (size_t)Bn * Cn;
  float* out_scalars = out + (size_t)Bn * Cn + Bn;

  aconv_k<<<dim3(NKT, Bn / 128, Hn), 256, 0, stream>>>(feats, AhG, AlG);
  bconv_k<<<dim3(NKT, Cpad / 128, Hn), 256, 0, stream>>>(W, BhG, BlG);
  gemm_k<<<dim3(Cpad / 128, Bn / 128, Hn * KSPLIT), 256, 0, stream>>>(
      AhG, AlG, BhG, BlG, bias, logits);
  conf_k<<<(Hn * Bn) / 4, 256, 0, stream>>>(logits, ms, ss, out_scalars);
  pick_k<<<Bn, 256, 0, stream>>>(logits, ms, ss, y, out, out_exit, out_scalars);
}

// Round 8
// 197.221 us; speedup vs baseline: 1.4271x; 1.0051x over previous
//
#include <hip/hip_runtime.h>
#include <math.h>

#define Hn 6
#define Bn 512
#define Dn 2048
#define Cn 1000
#define Cpad 1024
#define TAUv 0.5f
#define KSPLIT 2
#define KPER (Dn / KSPLIT)   // 1024
#define KT 32
#define NIT (KPER / KT)      // 32 k-iters per block
#define NKT (Dn / KT)        // 64 ktiles total

typedef unsigned int u32;
typedef unsigned short u16;
typedef __attribute__((ext_vector_type(8))) short short8;
typedef __attribute__((ext_vector_type(4))) float f32x4;

union FragU { u32 d[4]; short8 s; };

__device__ __forceinline__ u32 bf16_rne(float f) {
  const u32 u = __float_as_uint(f);
  return (u + 0x7FFFu + ((u >> 16) & 1u)) >> 16;
}
// pack two floats to one dword of bf16 (RNE; f0 -> low half), return residuals
__device__ __forceinline__ u32 pack_rne2(float f0, float f1, float& r0, float& r1) {
  const u32 b0 = bf16_rne(f0), b1 = bf16_rne(f1);
  r0 = f0 - __uint_as_float(b0 << 16);
  r1 = f1 - __uint_as_float(b1 << 16);
  return b0 | (b1 << 16);
}

// async global->LDS DMA, 16 B/lane; global vaddr per-lane, LDS dest = uniform base + lane*16
__device__ __forceinline__ void dma16(const void* g, void* l) {
  __builtin_amdgcn_global_load_lds(
      (const __attribute__((address_space(1))) u32*)g,
      (__attribute__((address_space(3))) u32*)l, 16, 0, 0);
}

// convert 8 fp32 -> hi/lo bf16 16B chunks
__device__ __forceinline__ void pack8(const float* rr, uint4& hv, uint4& lv) {
  float x0, x1, x2, x3, y0, y1, y2, y3, d;
  hv.x = pack_rne2(rr[0], rr[1], x0, x1);
  hv.y = pack_rne2(rr[2], rr[3], x2, x3);
  hv.z = pack_rne2(rr[4], rr[5], y0, y1);
  hv.w = pack_rne2(rr[6], rr[7], y2, y3);
  lv.x = pack_rne2(x0, x1, d, d);
  lv.y = pack_rne2(x2, x3, d, d);
  lv.z = pack_rne2(y0, y1, d, d);
  lv.w = pack_rne2(y2, y3, d, d);
}

// ============ feats fp32 [H][B][D] -> k-tiled Ah/Al: [H][64][4][512][8] ============
__global__ __launch_bounds__(256) void aconv_k(const float* __restrict__ feats,
                                               u16* __restrict__ Ah, u16* __restrict__ Al)
{
  const int t  = blockIdx.x;    // ktile 0..63
  const int rg = blockIdx.y;    // row group 0..3
  const int h  = blockIdx.z;
  const int r0 = rg * 128;
  __shared__ float tile[128][33];
  const int tid = threadIdx.x;

#pragma unroll
  for (int i = 0; i < 4; ++i) {
    const int f = i * 256 + tid;     // 0..1023 float4 tasks
    const int r = f >> 3, q = f & 7;
    const float4 v = *(const float4*)(feats + ((size_t)(h * Bn + r0 + r) * Dn + t * 32 + q * 4));
    tile[r][q * 4 + 0] = v.x; tile[r][q * 4 + 1] = v.y;
    tile[r][q * 4 + 2] = v.z; tile[r][q * 4 + 3] = v.w;
  }
  __syncthreads();
#pragma unroll
  for (int i = 0; i < 2; ++i) {
    const int j = i * 256 + tid;     // 0..511 chunk tasks
    const int c = j >> 7, r = j & 127;
    float rr[8];
#pragma unroll
    for (int e = 0; e < 8; ++e) rr[e] = tile[r][c * 8 + e];
    uint4 hv, lv;
    pack8(rr, hv, lv);
    const size_t o = (((size_t)(h * 64 + t) * 4 + c) * 512 + r0 + r);
    ((uint4*)Ah)[o] = hv;
    ((uint4*)Al)[o] = lv;
  }
}

// ============ W fp32 [H][D][C] -> k-tiled transposed Bh/Bl: [H][64][4][1024][8] ============
__global__ __launch_bounds__(256) void bconv_k(const float* __restrict__ W,
                                               u16* __restrict__ Bh, u16* __restrict__ Bl)
{
  const int t  = blockIdx.x;    // ktile 0..63
  const int ng = blockIdx.y;    // n group 0..7
  const int h  = blockIdx.z;
  const int n0 = ng * 128;
  __shared__ float tile[32][129];
  const int tid = threadIdx.x;

#pragma unroll
  for (int i = 0; i < 4; ++i) {
    const int f = i * 256 + tid;     // 0..1023
    const int k = f >> 5, q = f & 31;
    const int n = n0 + q * 4;
    const float* src = W + ((size_t)h * Dn + t * 32 + k) * Cn;
    float4 v = make_float4(0.f, 0.f, 0.f, 0.f);
    if (n + 3 < Cn) {
      v = *(const float4*)(src + n);
    } else {
      if (n + 0 < Cn) v.x = src[n + 0];
      if (n + 1 < Cn) v.y = src[n + 1];
      if (n + 2 < Cn) v.z = src[n + 2];
      if (n + 3 < Cn) v.w = src[n + 3];
    }
    tile[k][q * 4 + 0] = v.x; tile[k][q * 4 + 1] = v.y;
    tile[k][q * 4 + 2] = v.z; tile[k][q * 4 + 3] = v.w;
  }
  __syncthreads();
#pragma unroll
  for (int i = 0; i < 2; ++i) {
    const int j = i * 256 + tid;     // 0..511
    const int c = j >> 7, n = j & 127;
    float rr[8];
#pragma unroll
    for (int e = 0; e < 8; ++e) rr[e] = tile[c * 8 + e][n];
    uint4 hv, lv;
    pack8(rr, hv, lv);
    const size_t o = (((size_t)(h * 64 + t) * 4 + c) * 1024 + n0 + n);
    ((uint4*)Bh)[o] = hv;
    ((uint4*)Bl)[o] = lv;
  }
}

// ============ split-bf16 MFMA GEMM: 128x64 block, 2 waves, wave-tile 64x64 ============
// KSPLIT=2 partials; per wave-iter: 12 coalesced DMA + 16 ds_read_b128 + 48 MFMA.
// LDS 24 KB -> 6 blocks/CU resident (12 waves), 768-block grid.
__global__ __launch_bounds__(128, 3) void gemm_k(
    const u16* __restrict__ AhG, const u16* __restrict__ AlG,
    const u16* __restrict__ BhG, const u16* __restrict__ BlG,
    const float* __restrict__ bias, float* __restrict__ logits)
{
  const int h  = blockIdx.z >> 1;
  const int kz = blockIdx.z & 1;
  const int m0 = blockIdx.y * 128;
  const int n0 = blockIdx.x * 64;

  __shared__ __align__(16) short Ah[4][128][8];   // 8 KB
  __shared__ __align__(16) short Al[4][128][8];   // 8 KB
  __shared__ __align__(16) short Bh[4][64][8];    // 4 KB
  __shared__ __align__(16) short Bl[4][64][8];    // 4 KB

  const int t = threadIdx.x;      // 0..127
  const int lane = t & 63;
  const int w    = t >> 6;        // 2 waves: 0 stages hi, 1 stages lo
  const int wm   = w * 64;        // wave m-offset
  const int fl   = lane & 15;
  const int fq   = lane >> 4;

  const u16* Ag = w ? AlG : AhG;
  const u16* Bg = w ? BlG : BhG;
  short* Ald = w ? &Al[0][0][0] : &Ah[0][0][0];
  short* Bld = w ? &Bl[0][0][0] : &Bh[0][0][0];

  const int kt0 = kz * NIT;   // starting ktile
  // uint4 units (= one [8]-short group)
  const uint4* gA = (const uint4*)Ag + ((size_t)(h * 64 + kt0) * 4) * 512 + m0 + lane;
  const uint4* gB = (const uint4*)Bg + ((size_t)(h * 64 + kt0) * 4) * 1024 + n0 + lane;

  f32x4 acc[4][4];
#pragma unroll
  for (int i = 0; i < 4; ++i)
#pragma unroll
    for (int j = 0; j < 4; ++j) acc[i][j] = (f32x4){0.f, 0.f, 0.f, 0.f};

  for (int it = 0; it < NIT; ++it) {
    // 12 DMA per wave, each a fully-coalesced 1 KB burst
#pragma unroll
    for (int c = 0; c < 4; ++c) {
      const size_t ao = (size_t)(it * 4 + c) * 512;
      const size_t bo = (size_t)(it * 4 + c) * 1024;
      dma16(gA + ao,      Ald + (c * 128) * 8);        // A rows 0..63
      dma16(gA + ao + 64, Ald + (c * 128 + 64) * 8);   // A rows 64..127
      dma16(gB + bo,      Bld + (c * 64) * 8);         // B rows 0..63
    }
    __syncthreads();   // vmcnt drain: this tile landed, prior reads done

    FragU ah[4], al[4];
#pragma unroll
    for (int mt = 0; mt < 4; ++mt) {
      const int m = wm + mt * 16 + fl;
      ah[mt].s = *(const short8*)(&Ah[fq][m][0]);
      al[mt].s = *(const short8*)(&Al[fq][m][0]);
    }
#pragma unroll
    for (int nt = 0; nt < 4; ++nt) {
      const int n = nt * 16 + fl;
      FragU bh, bl;
      bh.s = *(const short8*)(&Bh[fq][n][0]);
      bl.s = *(const short8*)(&Bl[fq][n][0]);
#pragma unroll
      for (int mt = 0; mt < 4; ++mt) {
        acc[mt][nt] = __builtin_amdgcn_mfma_f32_16x16x32_bf16(ah[mt].s, bh.s, acc[mt][nt], 0, 0, 0);
        acc[mt][nt] = __builtin_amdgcn_mfma_f32_16x16x32_bf16(ah[mt].s, bl.s, acc[mt][nt], 0, 0, 0);
        acc[mt][nt] = __builtin_amdgcn_mfma_f32_16x16x32_bf16(al[mt].s, bh.s, acc[mt][nt], 0, 0, 0);
      }
    }
    __syncthreads();   // all reads done before next iter's DMA overwrites
  }

  // epilogue: plain stores into this kz's partial (+bias on kz 0)
  float* part = logits + (size_t)kz * ((size_t)Hn * Bn * Cn);
#pragma unroll
  for (int nt = 0; nt < 4; ++nt) {
    const int col = n0 + nt * 16 + fl;
    if (col >= Cn) continue;
    const float bv = (kz == 0) ? bias[(size_t)h * Cn + col] : 0.f;
#pragma unroll
    for (int mt = 0; mt < 4; ++mt) {
      const int rbase = m0 + wm + mt * 16 + fq * 4;
#pragma unroll
      for (int r = 0; r < 4; ++r)
        part[((size_t)h * Bn + rbase + r) * Cn + col] = acc[mt][nt][r] + bv;
    }
  }
}

// ============ per-row softmax stats over summed partials: one wave per (h,b) ============
__global__ __launch_bounds__(256) void conf_k(const float* __restrict__ logits,
                                              float* __restrict__ ms,
                                              float* __restrict__ ss,
                                              float* __restrict__ scalars)
{
  if (blockIdx.x == 0 && threadIdx.x == 0) { scalars[0] = 0.f; scalars[1] = 0.f; }
  const int w = threadIdx.x >> 6, lane = threadIdx.x & 63;
  const int r = blockIdx.x * 4 + w;                 // row = h*Bn + b
  const float* p = logits + (size_t)r * Cn;
  const size_t S = (size_t)Hn * Bn * Cn;

  float vv[16];
#pragma unroll
  for (int i = 0; i < 4; ++i) {
    const int c4 = i * 256 + lane * 4;
    if (c4 + 3 < Cn) {
      const float4 v0 = *(const float4*)(p + c4);
      const float4 v1 = *(const float4*)(p + S + c4);
      vv[4 * i + 0] = v0.x + v1.x;
      vv[4 * i + 1] = v0.y + v1.y;
      vv[4 * i + 2] = v0.z + v1.z;
      vv[4 * i + 3] = v0.w + v1.w;
    } else {
#pragma unroll
      for (int j = 0; j < 4; ++j) {
        const int c = c4 + j;
        vv[4 * i + j] = (c < Cn) ? p[c] + p[S + c] : -3.4e38f;
      }
    }
  }
  float m = -3.4e38f;
#pragma unroll
  for (int i = 0; i < 16; ++i) m = fmaxf(m, vv[i]);
#pragma unroll
  for (int off = 32; off >= 1; off >>= 1) m = fmaxf(m, __shfl_xor(m, off));
  float s = 0.f;
#pragma unroll
  for (int i = 0; i < 16; ++i) s += (vv[i] > -3.0e38f) ? expf(vv[i] - m) : 0.f;
#pragma unroll
  for (int off = 32; off >= 1; off >>= 1) s += __shfl_xor(s, off);
  if (lane == 0) { ms[r] = m; ss[r] = s; }
}

// ============ route + gather (summed partials) + argmax + CE ============
__global__ __launch_bounds__(256) void pick_k(
    const float* __restrict__ logits, const float* __restrict__ ms,
    const float* __restrict__ ss, const int* __restrict__ y,
    float* __restrict__ out, float* __restrict__ out_exit,
    float* __restrict__ scalars)
{
  const int b = blockIdx.x, t = threadIdx.x;
  const size_t S = (size_t)Hn * Bn * Cn;

  int first = -1, best = 0;
  float bestc = -3.4e38f;
#pragma unroll
  for (int h = 0; h < Hn; ++h) {
    const float c = 1.0f / ss[h * Bn + b];          // max softmax prob
    if (first < 0 && c >= TAUv) first = h;
    if (c > bestc) { bestc = c; best = h; }         // strict > keeps first occurrence
  }
  const int ex = (first >= 0) ? first : best;
  const float* p = logits + ((size_t)ex * Bn + b) * Cn;

  const int c4 = t * 4;
  float vv[4] = {-3.4e38f, -3.4e38f, -3.4e38f, -3.4e38f};
  if (c4 + 3 < Cn) {
    const float4 v0 = *(const float4*)(p + c4);
    const float4 v1 = *(const float4*)(p + S + c4);
    vv[0] = v0.x + v1.x;
    vv[1] = v0.y + v1.y;
    vv[2] = v0.z + v1.z;
    vv[3] = v0.w + v1.w;
  }
  float vm = -3.4e38f; int im = 1 << 30;
#pragma unroll
  for (int j = 0; j < 4; ++j) {
    const int c = c4 + j;
    if (c < Cn) {
      out[(size_t)b * Cn + c] = vv[j];
      if (vv[j] > vm) { vm = vv[j]; im = c; }       // ascending c keeps first max
    }
  }
  const int lane = t & 63, w = t >> 6;
#pragma unroll
  for (int off = 32; off >= 1; off >>= 1) {
    const float ov = __shfl_xor(vm, off);
    const int   oi = __shfl_xor(im, off);
    if (ov > vm || (ov == vm && oi < im)) { vm = ov; im = oi; }
  }
  __shared__ float rm[4]; __shared__ int ri[4];
  if (lane == 0) { rm[w] = vm; ri[w] = im; }
  __syncthreads();
  if (t == 0) {
    float bm = rm[0]; int bi = ri[0];
    for (int q = 1; q < 4; ++q)
      if (rm[q] > bm || (rm[q] == bm && ri[q] < bi)) { bm = rm[q]; bi = ri[q]; }
    const int yt = y[b];
    const float ryt = p[yt] + p[S + yt];
    const float lp = ryt - ms[ex * Bn + b] - logf(ss[ex * Bn + b]);
    out_exit[b] = (float)ex;
    atomicAdd(&scalars[0], -lp * (1.0f / (float)Bn));
    atomicAdd(&scalars[1], ((bi == yt) ? 1.f : 0.f) * (1.0f / (float)Bn));
  }
}

extern "C" void kernel_launch(void* const* d_in, const int* in_sizes, int n_in,
                              void* d_out, int out_size, void* d_ws, size_t ws_size,
                              hipStream_t stream) {
  const float* feats = (const float*)d_in[0];   // [H,B,D]
  const float* W     = (const float*)d_in[1];   // [H,D,C]
  const float* bias  = (const float*)d_in[2];   // [H,C]
  const int*   y     = (const int*)d_in[3];     // [B]
  float* out = (float*)d_out;                   // [B*C | B | 1 | 1]

  // ws layout:
  //   logits partials  KSPLIT * H*B*C f32 = 24,576,000 B
  //   ms, ss           H*B f32 each
  //   AhG, AlG         [H][64][4][512][8]  bf16 = 12,582,912 B each
  //   BhG, BlG         [H][64][4][1024][8] bf16 = 25,165,824 B each
  //   total ~100.2 MB
  float* logits = (float*)d_ws;
  float* ms     = logits + (size_t)KSPLIT * Hn * Bn * Cn;
  float* ss     = ms + Hn * Bn;
  u16*   AhG    = (u16*)(ss + Hn * Bn);
  u16*   AlG    = AhG + (size_t)Hn * Bn * Dn;
  u16*   BhG    = AlG + (size_t)Hn * Bn * Dn;
  u16*   BlG    = BhG + (size_t)Hn * Cpad * Dn;

  float* out_exit    = out + (size_t)Bn * Cn;
  float* out_scalars = out + (size_t)Bn * Cn + Bn;

  aconv_k<<<dim3(NKT, Bn / 128, Hn), 256, 0, stream>>>(feats, AhG, AlG);
  bconv_k<<<dim3(NKT, Cpad / 128, Hn), 256, 0, stream>>>(W, BhG, BlG);
  gemm_k<<<dim3(Cpad / 64, Bn / 128, Hn * KSPLIT), 128, 0, stream>>>(
      AhG, AlG, BhG, BlG, bias, logits);
  conf_k<<<(Hn * Bn) / 4, 256, 0, stream>>>(logits, ms, ss, out_scalars);
  pick_k<<<Bn, 256, 0, stream>>>(logits, ms, ss, y, out, out_exit, out_scalars);
}

// Round 9
// 187.999 us; speedup vs baseline: 1.4971x; 1.0491x over previous
//
#include <hip/hip_runtime.h>
#include <math.h>

#define Hn 6
#define Bn 512
#define Dn 2048
#define Cn 1000
#define Cpad 1024
#define TAUv 0.5f
#define KSPLIT 4
#define KPER (Dn / KSPLIT)   // 512
#define KT 32
#define NIT (KPER / KT)      // 16 k-iters per gemm block
#define NKT (Dn / KT)        // 64 ktiles total

typedef unsigned int u32;
typedef unsigned short u16;
typedef __attribute__((ext_vector_type(8))) short short8;
typedef __attribute__((ext_vector_type(4))) float f32x4;

union FragU { u32 d[4]; short8 s; };

__device__ __forceinline__ u32 bf16_rne(float f) {
  const u32 u = __float_as_uint(f);
  return (u + 0x7FFFu + ((u >> 16) & 1u)) >> 16;
}
// pack two floats to one dword of bf16 (RNE; f0 -> low half), return residuals
__device__ __forceinline__ u32 pack_rne2(float f0, float f1, float& r0, float& r1) {
  const u32 b0 = bf16_rne(f0), b1 = bf16_rne(f1);
  r0 = f0 - __uint_as_float(b0 << 16);
  r1 = f1 - __uint_as_float(b1 << 16);
  return b0 | (b1 << 16);
}

// async global->LDS DMA, 16 B/lane; LDS dest = wave-uniform base + lane*16
__device__ __forceinline__ void dma16(const void* g, void* l) {
  __builtin_amdgcn_global_load_lds(
      (const __attribute__((address_space(1))) u32*)g,
      (__attribute__((address_space(3))) u32*)l, 16, 0, 0);
}

// convert 8 fp32 -> hi/lo bf16 16B chunks
__device__ __forceinline__ void pack8(const float* rr, uint4& hv, uint4& lv) {
  float x0, x1, x2, x3, y0, y1, y2, y3, d;
  hv.x = pack_rne2(rr[0], rr[1], x0, x1);
  hv.y = pack_rne2(rr[2], rr[3], x2, x3);
  hv.z = pack_rne2(rr[4], rr[5], y0, y1);
  hv.w = pack_rne2(rr[6], rr[7], y2, y3);
  lv.x = pack_rne2(x0, x1, d, d);
  lv.y = pack_rne2(x2, x3, d, d);
  lv.z = pack_rne2(y0, y1, d, d);
  lv.w = pack_rne2(y2, y3, d, d);
}

// ============ fused conversion kernel ============
// blockIdx.y < 4 : feats [H][B][D] -> k-tiled Ah/Al [H][64][4][512][8]   (rg = y)
// blockIdx.y >= 4: W [H][D][C] -> k-tiled transposed Bh/Bl [H][64][4][1024][8] (ng = y-4)
__global__ __launch_bounds__(256) void conv_k(
    const float* __restrict__ feats, const float* __restrict__ W,
    u16* __restrict__ Ah, u16* __restrict__ Al,
    u16* __restrict__ Bh, u16* __restrict__ Bl,
    float* __restrict__ scalars)
{
  __shared__ float smem[128 * 33];   // aconv: [128][33]; bconv: [32][129]
  const int t   = blockIdx.x;        // ktile 0..63
  const int yy  = blockIdx.y;        // 0..11
  const int h   = blockIdx.z;
  const int tid = threadIdx.x;

  if (t == 0 && yy == 0 && h == 0 && tid == 0) { scalars[0] = 0.f; scalars[1] = 0.f; }

  if (yy < 4) {
    // ---------------- A path ----------------
    const int r0 = yy * 128;
#pragma unroll
    for (int i = 0; i < 4; ++i) {
      const int f = i * 256 + tid;     // 0..1023 float4 tasks
      const int r = f >> 3, q = f & 7;
      const float4 v = *(const float4*)(feats + ((size_t)(h * Bn + r0 + r) * Dn + t * 32 + q * 4));
      smem[r * 33 + q * 4 + 0] = v.x; smem[r * 33 + q * 4 + 1] = v.y;
      smem[r * 33 + q * 4 + 2] = v.z; smem[r * 33 + q * 4 + 3] = v.w;
    }
    __syncthreads();
#pragma unroll
    for (int i = 0; i < 2; ++i) {
      const int j = i * 256 + tid;     // 0..511 chunk tasks
      const int c = j >> 7, r = j & 127;
      float rr[8];
#pragma unroll
      for (int e = 0; e < 8; ++e) rr[e] = smem[r * 33 + c * 8 + e];
      uint4 hv, lv;
      pack8(rr, hv, lv);
      const size_t o = (((size_t)(h * 64 + t) * 4 + c) * 512 + r0 + r);
      ((uint4*)Ah)[o] = hv;
      ((uint4*)Al)[o] = lv;
    }
  } else {
    // ---------------- B path (transpose) ----------------
    const int n0 = (yy - 4) * 128;
#pragma unroll
    for (int i = 0; i < 4; ++i) {
      const int f = i * 256 + tid;     // 0..1023
      const int k = f >> 5, q = f & 31;
      const int n = n0 + q * 4;
      const float* src = W + ((size_t)h * Dn + t * 32 + k) * Cn;
      float4 v = make_float4(0.f, 0.f, 0.f, 0.f);
      if (n + 3 < Cn) {
        v = *(const float4*)(src + n);
      } else {
        if (n + 0 < Cn) v.x = src[n + 0];
        if (n + 1 < Cn) v.y = src[n + 1];
        if (n + 2 < Cn) v.z = src[n + 2];
        if (n + 3 < Cn) v.w = src[n + 3];
      }
      smem[k * 129 + q * 4 + 0] = v.x; smem[k * 129 + q * 4 + 1] = v.y;
      smem[k * 129 + q * 4 + 2] = v.z; smem[k * 129 + q * 4 + 3] = v.w;
    }
    __syncthreads();
#pragma unroll
    for (int i = 0; i < 2; ++i) {
      const int j = i * 256 + tid;     // 0..511
      const int c = j >> 7, n = j & 127;
      float rr[8];
#pragma unroll
      for (int e = 0; e < 8; ++e) rr[e] = smem[(c * 8 + e) * 129 + n];
      uint4 hv, lv;
      pack8(rr, hv, lv);
      const size_t o = (((size_t)(h * 64 + t) * 4 + c) * 1024 + n0 + n);
      ((uint4*)Bh)[o] = hv;
      ((uint4*)Bl)[o] = lv;
    }
  }
}

// ============ split-bf16 MFMA GEMM (R7 config: best measured, 51 us) ============
// 128x128 block, 256 thr = 4 waves (2x2), wave-tile 64x64, 3-term split-bf16,
// KSPLIT=4 partials, coalesced k-tiled DMA staging, 768-block grid.
__global__ __launch_bounds__(256, 3) void gemm_k(
    const u16* __restrict__ AhG, const u16* __restrict__ AlG,
    const u16* __restrict__ BhG, const u16* __restrict__ BlG,
    const float* __restrict__ bias, float* __restrict__ logits)
{
  const int h  = blockIdx.z >> 2;
  const int kz = blockIdx.z & 3;
  const int m0 = blockIdx.y * 128;
  const int n0 = blockIdx.x * 128;

  __shared__ __align__(16) short Ah[4][128][8];   // 8 KB each
  __shared__ __align__(16) short Al[4][128][8];
  __shared__ __align__(16) short Bh[4][128][8];
  __shared__ __align__(16) short Bl[4][128][8];

  const int t = threadIdx.x;
  const int lane = t & 63;
  const int w    = t >> 6;
  const int wm   = (w & 1) * 64;
  const int wn   = (w >> 1) * 64;
  const int fl   = lane & 15;
  const int fq   = lane >> 4;

  // wave w stages matrix w; k-tiled layout -> each dma16 is a 1KB coalesced burst
  const u16* gmat = (w == 0) ? AhG : (w == 1) ? AlG : (w == 2) ? BhG : BlG;
  const int  R    = (w < 2) ? 512 : 1024;
  const int  row0 = (w < 2) ? m0 : n0;
  short* lbase = (w == 0) ? &Ah[0][0][0] : (w == 1) ? &Al[0][0][0]
               : (w == 2) ? &Bh[0][0][0] : &Bl[0][0][0];
  const uint4* g0 = (const uint4*)gmat
                  + ((size_t)(h * 64 + kz * NIT) * 4) * R + row0 + lane;

  f32x4 acc[4][4];
#pragma unroll
  for (int i = 0; i < 4; ++i)
#pragma unroll
    for (int j = 0; j < 4; ++j) acc[i][j] = (f32x4){0.f, 0.f, 0.f, 0.f};

  for (int it = 0; it < NIT; ++it) {
    const size_t ito = (size_t)(it * 4) * R;
#pragma unroll
    for (int c = 0; c < 4; ++c) {
      dma16(g0 + ito + (size_t)c * R,      lbase + (c * 128) * 8);        // rows 0..63
      dma16(g0 + ito + (size_t)c * R + 64, lbase + (c * 128 + 64) * 8);   // rows 64..127
    }
    __syncthreads();   // vmcnt(0) drain: DMA landed

    FragU ah[4], al[4];
#pragma unroll
    for (int mt = 0; mt < 4; ++mt) {
      const int m = wm + mt * 16 + fl;
      ah[mt].s = *(const short8*)(&Ah[fq][m][0]);
      al[mt].s = *(const short8*)(&Al[fq][m][0]);
    }
#pragma unroll
    for (int nt = 0; nt < 4; ++nt) {
      const int n = wn + nt * 16 + fl;
      FragU bh, bl;
      bh.s = *(const short8*)(&Bh[fq][n][0]);
      bl.s = *(const short8*)(&Bl[fq][n][0]);
#pragma unroll
      for (int mt = 0; mt < 4; ++mt) {
        acc[mt][nt] = __builtin_amdgcn_mfma_f32_16x16x32_bf16(ah[mt].s, bh.s, acc[mt][nt], 0, 0, 0);
        acc[mt][nt] = __builtin_amdgcn_mfma_f32_16x16x32_bf16(ah[mt].s, bl.s, acc[mt][nt], 0, 0, 0);
        acc[mt][nt] = __builtin_amdgcn_mfma_f32_16x16x32_bf16(al[mt].s, bh.s, acc[mt][nt], 0, 0, 0);
      }
    }
    __syncthreads();   // all reads done before next iter's DMA overwrites
  }

  // epilogue: plain stores into this kz's partial (+bias on kz 0)
  float* part = logits + (size_t)kz * ((size_t)Hn * Bn * Cn);
#pragma unroll
  for (int nt = 0; nt < 4; ++nt) {
    const int col = n0 + wn + nt * 16 + fl;
    if (col >= Cn) continue;
    const float bv = (kz == 0) ? bias[(size_t)h * Cn + col] : 0.f;
#pragma unroll
    for (int mt = 0; mt < 4; ++mt) {
      const int rbase = m0 + wm + mt * 16 + fq * 4;
#pragma unroll
      for (int r = 0; r < 4; ++r)
        part[((size_t)h * Bn + rbase + r) * Cn + col] = acc[mt][nt][r] + bv;
    }
  }
}

// ============ fused conf + route + gather + CE: one block per sample ============
// 4 waves; wave-per-row softmax stats (2 passes over 6 rows, shuffle-only),
// then uniform route, then whole-block gather of the chosen row.
__global__ __launch_bounds__(256) void confpick_k(
    const float* __restrict__ logits, const int* __restrict__ y,
    float* __restrict__ out, float* __restrict__ out_exit,
    float* __restrict__ scalars)
{
  const int b = blockIdx.x, tid = threadIdx.x;
  const int lane = tid & 63, w = tid >> 6;
  const size_t S = (size_t)Hn * Bn * Cn;
  __shared__ float ms[Hn], ss[Hn];

  // ---- per-row softmax stats: wave w covers rows w and w+4 ----
  for (int h = w; h < Hn; h += 4) {
    const float* p = logits + ((size_t)h * Bn + b) * Cn;
    float vv[16];
#pragma unroll
    for (int i = 0; i < 4; ++i) {
      const int c4 = i * 256 + lane * 4;
      if (c4 + 3 < Cn) {
        const float4 v0 = *(const float4*)(p + c4);
        const float4 v1 = *(const float4*)(p + S + c4);
        const float4 v2 = *(const float4*)(p + 2 * S + c4);
        const float4 v3 = *(const float4*)(p + 3 * S + c4);
        vv[4 * i + 0] = v0.x + v1.x + v2.x + v3.x;
        vv[4 * i + 1] = v0.y + v1.y + v2.y + v3.y;
        vv[4 * i + 2] = v0.z + v1.z + v2.z + v3.z;
        vv[4 * i + 3] = v0.w + v1.w + v2.w + v3.w;
      } else {
#pragma unroll
        for (int j = 0; j < 4; ++j) {
          const int c = c4 + j;
          vv[4 * i + j] = (c < Cn) ? p[c] + p[S + c] + p[2 * S + c] + p[3 * S + c]
                                   : -3.4e38f;
        }
      }
    }
    float m = -3.4e38f;
#pragma unroll
    for (int i = 0; i < 16; ++i) m = fmaxf(m, vv[i]);
#pragma unroll
    for (int off = 32; off >= 1; off >>= 1) m = fmaxf(m, __shfl_xor(m, off));
    float s = 0.f;
#pragma unroll
    for (int i = 0; i < 16; ++i) s += (vv[i] > -3.0e38f) ? expf(vv[i] - m) : 0.f;
#pragma unroll
    for (int off = 32; off >= 1; off >>= 1) s += __shfl_xor(s, off);
    if (lane == 0) { ms[h] = m; ss[h] = s; }
  }
  __syncthreads();

  // ---- route (uniform across block, from LDS stats) ----
  int first = -1, best = 0;
  float bestc = -3.4e38f;
#pragma unroll
  for (int h = 0; h < Hn; ++h) {
    const float c = 1.0f / ss[h];                   // max softmax prob
    if (first < 0 && c >= TAUv) first = h;
    if (c > bestc) { bestc = c; best = h; }         // strict > keeps first occurrence
  }
  const int ex = (first >= 0) ? first : best;
  const float* p = logits + ((size_t)ex * Bn + b) * Cn;

  // ---- gather chosen row (L2-warm re-read), argmax, store ----
  const int c4 = tid * 4;
  float vv[4] = {-3.4e38f, -3.4e38f, -3.4e38f, -3.4e38f};
  if (c4 + 3 < Cn) {
    const float4 v0 = *(const float4*)(p + c4);
    const float4 v1 = *(const float4*)(p + S + c4);
    const float4 v2 = *(const float4*)(p + 2 * S + c4);
    const float4 v3 = *(const float4*)(p + 3 * S + c4);
    vv[0] = v0.x + v1.x + v2.x + v3.x;
    vv[1] = v0.y + v1.y + v2.y + v3.y;
    vv[2] = v0.z + v1.z + v2.z + v3.z;
    vv[3] = v0.w + v1.w + v2.w + v3.w;
  }
  float vm = -3.4e38f; int im = 1 << 30;
#pragma unroll
  for (int j = 0; j < 4; ++j) {
    const int c = c4 + j;
    if (c < Cn) {
      out[(size_t)b * Cn + c] = vv[j];
      if (vv[j] > vm) { vm = vv[j]; im = c; }       // ascending c keeps first max
    }
  }
#pragma unroll
  for (int off = 32; off >= 1; off >>= 1) {
    const float ov = __shfl_xor(vm, off);
    const int   oi = __shfl_xor(im, off);
    if (ov > vm || (ov == vm && oi < im)) { vm = ov; im = oi; }
  }
  __shared__ float rm[4]; __shared__ int ri[4];
  if (lane == 0) { rm[w] = vm; ri[w] = im; }
  __syncthreads();
  if (tid == 0) {
    float bm = rm[0]; int bi = ri[0];
    for (int q = 1; q < 4; ++q)
      if (rm[q] > bm || (rm[q] == bm && ri[q] < bi)) { bm = rm[q]; bi = ri[q]; }
    const int yt = y[b];
    const float ryt = p[yt] + p[S + yt] + p[2 * S + yt] + p[3 * S + yt];
    const float lp = ryt - ms[ex] - logf(ss[ex]);
    out_exit[b] = (float)ex;
    atomicAdd(&scalars[0], -lp * (1.0f / (float)Bn));
    atomicAdd(&scalars[1], ((bi == yt) ? 1.f : 0.f) * (1.0f / (float)Bn));
  }
}

extern "C" void kernel_launch(void* const* d_in, const int* in_sizes, int n_in,
                              void* d_out, int out_size, void* d_ws, size_t ws_size,
                              hipStream_t stream) {
  const float* feats = (const float*)d_in[0];   // [H,B,D]
  const float* W     = (const float*)d_in[1];   // [H,D,C]
  const float* bias  = (const float*)d_in[2];   // [H,C]
  const int*   y     = (const int*)d_in[3];     // [B]
  float* out = (float*)d_out;                   // [B*C | B | 1 | 1]

  // ws layout:
  //   logits partials  KSPLIT * H*B*C f32 = 49,152,000 B
  //   AhG, AlG         [H][64][4][512][8]  bf16 = 12,582,912 B each
  //   BhG, BlG         [H][64][4][1024][8] bf16 = 25,165,824 B each
  float* logits = (float*)d_ws;
  u16*   AhG    = (u16*)(logits + (size_t)KSPLIT * Hn * Bn * Cn);
  u16*   AlG    = AhG + (size_t)Hn * Bn * Dn;
  u16*   BhG    = AlG + (size_t)Hn * Bn * Dn;
  u16*   BlG    = BhG + (size_t)Hn * Cpad * Dn;

  float* out_exit    = out + (size_t)Bn * Cn;
  float* out_scalars = out + (size_t)Bn * Cn + Bn;

  conv_k<<<dim3(NKT, 12, Hn), 256, 0, stream>>>(feats, W, AhG, AlG, BhG, BlG, out_scalars);
  gemm_k<<<dim3(Cpad / 128, Bn / 128, Hn * KSPLIT), 256, 0, stream>>>(
      AhG, AlG, BhG, BlG, bias, logits);
  confpick_k<<<Bn, 256, 0, stream>>>(logits, y, out, out_exit, out_scalars);
}